// Round 1
// baseline (2116.321 us; speedup 1.0000x reference)
//
#include <hip/hip_runtime.h>

#define FIN 100
#define FHID 100
#define FEMB 64
#define NCLS 40

// ---------- degree / dinv ----------
__global__ void k_init_deg(float* deg, int n) {
    int i = blockIdx.x * blockDim.x + threadIdx.x;
    if (i < n) deg[i] = 1.0f;  // self-loop
}

__global__ void k_accum_deg(const int* __restrict__ dst, float* deg, int E) {
    int e = blockIdx.x * blockDim.x + threadIdx.x;
    if (e < E) atomicAdd(&deg[dst[e]], 1.0f);
}

__global__ void k_dinv(float* deg, int n) {
    int i = blockIdx.x * blockDim.x + threadIdx.x;
    if (i < n) deg[i] = rsqrtf(deg[i]);  // deg >= 1 always
}

// ---------- GEMM: C[n,KOUT] = (relu?)A[n,KIN] @ W[KIN,KOUT] (+bias) ----------
template <int KIN, int KOUT, bool RELU_IN, bool BIAS>
__global__ __launch_bounds__(256) void k_gemm(const float* __restrict__ A,
                                              const float* __restrict__ W,
                                              const float* __restrict__ bias,
                                              float* __restrict__ C, int n) {
    __shared__ float Ws[KIN * KOUT];
    __shared__ float As[32 * KIN];
    const int row0 = blockIdx.x * 32;
    for (int i = threadIdx.x; i < KIN * KOUT; i += 256) Ws[i] = W[i];
    const int rows = min(32, n - row0);
    for (int i = threadIdx.x; i < rows * KIN; i += 256) {
        float v = A[(size_t)row0 * KIN + i];
        As[i] = RELU_IN ? fmaxf(v, 0.0f) : v;
    }
    __syncthreads();
    const int G = KOUT / 4;
    for (int task = threadIdx.x; task < rows * G; task += 256) {
        int r = task / G;
        int c = (task % G) * 4;
        float a0 = 0.f, a1 = 0.f, a2 = 0.f, a3 = 0.f;
        const float* as = &As[r * KIN];
        #pragma unroll 4
        for (int k = 0; k < KIN; ++k) {
            float a = as[k];
            const float4 w = *(const float4*)&Ws[k * KOUT + c];
            a0 = fmaf(a, w.x, a0);
            a1 = fmaf(a, w.y, a1);
            a2 = fmaf(a, w.z, a2);
            a3 = fmaf(a, w.w, a3);
        }
        if (BIAS) {
            a0 += bias[c]; a1 += bias[c + 1]; a2 += bias[c + 2]; a3 += bias[c + 3];
        }
        float4 o = make_float4(a0, a1, a2, a3);
        *(float4*)&C[(size_t)(row0 + r) * KOUT + c] = o;
    }
}

// ---------- aggregation init: out = bias + h*dinv^2 (self-loop term) ----------
template <int F>
__global__ void k_agg_init(const float* __restrict__ h, const float* __restrict__ dinv,
                           const float* __restrict__ bias, float* __restrict__ out, int n) {
    const int G = F / 4;
    int gid = blockIdx.x * blockDim.x + threadIdx.x;
    if (gid >= n * G) return;
    int i = gid / G;
    int c = (gid % G) * 4;
    float d = dinv[i];
    float s = d * d;
    float4 v = *(const float4*)&h[(size_t)i * F + c];
    float4 b = *(const float4*)&bias[c];
    float4 o = make_float4(fmaf(v.x, s, b.x), fmaf(v.y, s, b.y),
                           fmaf(v.z, s, b.z), fmaf(v.w, s, b.w));
    *(float4*)&out[(size_t)i * F + c] = o;
}

// ---------- edge scatter: out[dst] += h[src] * dinv[src]*dinv[dst] ----------
template <int F>
__global__ void k_agg_edges(const float* __restrict__ h, const int* __restrict__ src,
                            const int* __restrict__ dst, const float* __restrict__ dinv,
                            float* __restrict__ out, int E) {
    const int G = F / 4;
    int gid = blockIdx.x * blockDim.x + threadIdx.x;
    if (gid >= E * G) return;
    int e = gid / G;
    int c = (gid % G) * 4;
    int s = src[e];
    int d = dst[e];
    float norm = dinv[s] * dinv[d];
    float4 v = *(const float4*)&h[(size_t)s * F + c];
    float* o = &out[(size_t)d * F + c];
    atomicAdd(o + 0, v.x * norm);
    atomicAdd(o + 1, v.y * norm);
    atomicAdd(o + 2, v.z * norm);
    atomicAdd(o + 3, v.w * norm);
}

extern "C" void kernel_launch(void* const* d_in, const int* in_sizes, int n_in,
                              void* d_out, int out_size, void* d_ws, size_t ws_size,
                              hipStream_t stream) {
    const float* x  = (const float*)d_in[0];
    const int*   ei = (const int*)d_in[1];
    const float* W1 = (const float*)d_in[2];
    const float* b1 = (const float*)d_in[3];
    const float* W2 = (const float*)d_in[4];
    const float* b2 = (const float*)d_in[5];
    const float* Wc = (const float*)d_in[6];
    const float* bc = (const float*)d_in[7];
    float* out = (float*)d_out;

    const int N = in_sizes[0] / FIN;
    const int E = in_sizes[1] / 2;
    const int* src = ei;
    const int* dst = ei + E;

    char* ws = (char*)d_ws;
    float* dinv = (float*)ws; ws += ((size_t)N * 4 + 255) / 256 * 256;
    float* h1   = (float*)ws; ws += (size_t)N * FHID * 4;
    float* a1   = (float*)ws; ws += (size_t)N * FHID * 4;
    float* h2   = (float*)ws; ws += (size_t)N * FEMB * 4;
    float* a2   = (float*)ws; ws += (size_t)N * FEMB * 4;

    const int B = 256;

    // degree + dinv
    k_init_deg<<<(N + B - 1) / B, B, 0, stream>>>(dinv, N);
    k_accum_deg<<<(E + B - 1) / B, B, 0, stream>>>(dst, dinv, E);
    k_dinv<<<(N + B - 1) / B, B, 0, stream>>>(dinv, N);

    // layer 1: h1 = x @ W1 ; a1 = agg(h1) + b1
    k_gemm<FIN, FHID, false, false><<<(N + 31) / 32, B, 0, stream>>>(x, W1, nullptr, h1, N);
    k_agg_init<FHID><<<((size_t)N * (FHID / 4) + B - 1) / B, B, 0, stream>>>(h1, dinv, b1, a1, N);
    k_agg_edges<FHID><<<((size_t)E * (FHID / 4) + B - 1) / B, B, 0, stream>>>(h1, src, dst, dinv, a1, E);

    // layer 2: h2 = relu(a1) @ W2 ; a2 = agg(h2) + b2
    k_gemm<FHID, FEMB, true, false><<<(N + 31) / 32, B, 0, stream>>>(a1, W2, nullptr, h2, N);
    k_agg_init<FEMB><<<((size_t)N * (FEMB / 4) + B - 1) / B, B, 0, stream>>>(h2, dinv, b2, a2, N);
    k_agg_edges<FEMB><<<((size_t)E * (FEMB / 4) + B - 1) / B, B, 0, stream>>>(h2, src, dst, dinv, a2, E);

    // classifier: out = relu(a2) @ Wc + bc
    k_gemm<FEMB, NCLS, true, true><<<(N + 31) / 32, B, 0, stream>>>(a2, Wc, bc, out, N);
}

// Round 2
// 342.451 us; speedup vs baseline: 6.1799x; 6.1799x over previous
//
#include <hip/hip_runtime.h>

#define FIN 100
#define FHID 100
#define FEMB 64
#define NCLS 40

// ================= CSR build (counting sort by dst) =================

__global__ void k_zero(int* __restrict__ cnt, int n) {
    int i = blockIdx.x * blockDim.x + threadIdx.x;
    if (i < n) cnt[i] = 0;
}

__global__ void k_count(const int* __restrict__ dst, int* __restrict__ cnt, int E) {
    int e = blockIdx.x * blockDim.x + threadIdx.x;
    if (e < E) atomicAdd(&cnt[dst[e]], 1);
}

// per-256-block exclusive scan; block sums to bsum
__global__ __launch_bounds__(256) void k_scan_block(const int* __restrict__ cnt,
                                                    int* __restrict__ row,
                                                    int* __restrict__ bsum, int n) {
    __shared__ int tmp[256];
    int idx = blockIdx.x * 256 + threadIdx.x;
    int v = (idx < n) ? cnt[idx] : 0;
    tmp[threadIdx.x] = v;
    __syncthreads();
    for (int off = 1; off < 256; off <<= 1) {
        int t = (threadIdx.x >= off) ? tmp[threadIdx.x - off] : 0;
        __syncthreads();
        tmp[threadIdx.x] += t;
        __syncthreads();
    }
    if (idx < n) row[idx] = tmp[threadIdx.x] - v;  // exclusive
    if (threadIdx.x == 255) bsum[blockIdx.x] = tmp[255];
}

// single-block exclusive scan of block sums (nb <= 256; N=50k -> nb=196)
__global__ __launch_bounds__(256) void k_scan_bsum(int* __restrict__ bsum, int nb) {
    __shared__ int tmp[256];
    int v = (threadIdx.x < nb) ? bsum[threadIdx.x] : 0;
    tmp[threadIdx.x] = v;
    __syncthreads();
    for (int off = 1; off < 256; off <<= 1) {
        int t = (threadIdx.x >= off) ? tmp[threadIdx.x - off] : 0;
        __syncthreads();
        tmp[threadIdx.x] += t;
        __syncthreads();
    }
    if (threadIdx.x < nb) bsum[threadIdx.x] = tmp[threadIdx.x] - v;
}

// rowptr += block offset; cursor = rowptr; dinv = rsqrt(deg+1); rowptr[n] = E
__global__ void k_finalize(int* __restrict__ row, const int* __restrict__ bsum,
                           int* __restrict__ cursor, const int* __restrict__ cnt,
                           float* __restrict__ dinv, int n, int E) {
    int i = blockIdx.x * blockDim.x + threadIdx.x;
    if (i < n) {
        int r = row[i] + bsum[i >> 8];
        row[i] = r;
        cursor[i] = r;
        dinv[i] = rsqrtf((float)cnt[i] + 1.0f);  // +1 self-loop
    }
    if (i == 0) row[n] = E;
}

__global__ void k_scatter(const int* __restrict__ src, const int* __restrict__ dst,
                          const float* __restrict__ dinv, int* __restrict__ cursor,
                          int* __restrict__ src_sorted, float* __restrict__ norm_sorted,
                          int E) {
    int e = blockIdx.x * blockDim.x + threadIdx.x;
    if (e >= E) return;
    int d = dst[e];
    int s = src[e];
    int pos = atomicAdd(&cursor[d], 1);
    src_sorted[pos] = s;
    norm_sorted[pos] = dinv[s] * dinv[d];
}

// ================= GEMM: C = (relu?)A @ W (+bias) =================
template <int KIN, int KOUT, bool RELU_IN, bool BIAS>
__global__ __launch_bounds__(256) void k_gemm(const float* __restrict__ A,
                                              const float* __restrict__ W,
                                              const float* __restrict__ bias,
                                              float* __restrict__ C, int n) {
    __shared__ float Ws[KIN * KOUT];
    __shared__ float As[32 * KIN];
    const int row0 = blockIdx.x * 32;
    for (int i = threadIdx.x; i < KIN * KOUT; i += 256) Ws[i] = W[i];
    const int rows = min(32, n - row0);
    for (int i = threadIdx.x; i < rows * KIN; i += 256) {
        float v = A[(size_t)row0 * KIN + i];
        As[i] = RELU_IN ? fmaxf(v, 0.0f) : v;
    }
    __syncthreads();
    const int G = KOUT / 4;
    for (int task = threadIdx.x; task < rows * G; task += 256) {
        int r = task / G;
        int c = (task % G) * 4;
        float a0 = 0.f, a1 = 0.f, a2 = 0.f, a3 = 0.f;
        const float* as = &As[r * KIN];
        #pragma unroll 4
        for (int k = 0; k < KIN; ++k) {
            float a = as[k];
            const float4 w = *(const float4*)&Ws[k * KOUT + c];
            a0 = fmaf(a, w.x, a0);
            a1 = fmaf(a, w.y, a1);
            a2 = fmaf(a, w.z, a2);
            a3 = fmaf(a, w.w, a3);
        }
        if (BIAS) {
            a0 += bias[c]; a1 += bias[c + 1]; a2 += bias[c + 2]; a3 += bias[c + 3];
        }
        *(float4*)&C[(size_t)(row0 + r) * KOUT + c] = make_float4(a0, a1, a2, a3);
    }
}

// ========== CSR aggregation: out[i] = bias + h[i]*dinv[i]^2 + sum_e h[src_e]*norm_e ==========
template <int F>
__global__ __launch_bounds__(256) void k_agg_csr(const float* __restrict__ h,
                                                 const int* __restrict__ rowptr,
                                                 const int* __restrict__ src_sorted,
                                                 const float* __restrict__ norm_sorted,
                                                 const float* __restrict__ dinv,
                                                 const float* __restrict__ bias,
                                                 float* __restrict__ out, int n) {
    const int G = F / 4;
    int gid = blockIdx.x * blockDim.x + threadIdx.x;
    if (gid >= n * G) return;
    int i = gid / G;
    int cq = gid % G;                    // float4 chunk index
    const float4* h4 = (const float4*)h;

    float d = dinv[i];
    float s = d * d;
    float4 hv = h4[(size_t)i * G + cq];
    float4 bv = *(const float4*)&bias[cq * 4];
    float4 acc = make_float4(fmaf(hv.x, s, bv.x), fmaf(hv.y, s, bv.y),
                             fmaf(hv.z, s, bv.z), fmaf(hv.w, s, bv.w));

    int beg = rowptr[i];
    int end = rowptr[i + 1];
    int e = beg;
    for (; e + 1 < end; e += 2) {
        int s0 = src_sorted[e];
        int s1 = src_sorted[e + 1];
        float n0 = norm_sorted[e];
        float n1 = norm_sorted[e + 1];
        float4 v0 = h4[(size_t)s0 * G + cq];
        float4 v1 = h4[(size_t)s1 * G + cq];
        acc.x = fmaf(v0.x, n0, acc.x); acc.y = fmaf(v0.y, n0, acc.y);
        acc.z = fmaf(v0.z, n0, acc.z); acc.w = fmaf(v0.w, n0, acc.w);
        acc.x = fmaf(v1.x, n1, acc.x); acc.y = fmaf(v1.y, n1, acc.y);
        acc.z = fmaf(v1.z, n1, acc.z); acc.w = fmaf(v1.w, n1, acc.w);
    }
    if (e < end) {
        int s0 = src_sorted[e];
        float n0 = norm_sorted[e];
        float4 v0 = h4[(size_t)s0 * G + cq];
        acc.x = fmaf(v0.x, n0, acc.x); acc.y = fmaf(v0.y, n0, acc.y);
        acc.z = fmaf(v0.z, n0, acc.z); acc.w = fmaf(v0.w, n0, acc.w);
    }
    ((float4*)out)[(size_t)i * G + cq] = acc;
}

extern "C" void kernel_launch(void* const* d_in, const int* in_sizes, int n_in,
                              void* d_out, int out_size, void* d_ws, size_t ws_size,
                              hipStream_t stream) {
    const float* x  = (const float*)d_in[0];
    const int*   ei = (const int*)d_in[1];
    const float* W1 = (const float*)d_in[2];
    const float* b1 = (const float*)d_in[3];
    const float* W2 = (const float*)d_in[4];
    const float* b2 = (const float*)d_in[5];
    const float* Wc = (const float*)d_in[6];
    const float* bc = (const float*)d_in[7];
    float* out = (float*)d_out;

    const int N = in_sizes[0] / FIN;
    const int E = in_sizes[1] / 2;
    const int* src = ei;
    const int* dst = ei + E;

    auto align = [](size_t v) { return (v + 255) & ~(size_t)255; };
    char* ws = (char*)d_ws;
    int*   deg_cnt     = (int*)ws;   ws += align((size_t)N * 4);
    int*   rowptr      = (int*)ws;   ws += align((size_t)(N + 1) * 4);
    int*   cursor      = (int*)ws;   ws += align((size_t)N * 4);
    int*   bsum        = (int*)ws;   ws += align(256 * 4);
    int*   src_sorted  = (int*)ws;   ws += align((size_t)E * 4);
    float* norm_sorted = (float*)ws; ws += align((size_t)E * 4);
    float* dinv        = (float*)ws; ws += align((size_t)N * 4);
    float* bufA        = (float*)ws; ws += align((size_t)N * FHID * 4);
    float* bufB        = (float*)ws; ws += align((size_t)N * FHID * 4);

    const int B = 256;
    const int nb = (N + 255) / 256;  // 196 for N=50k; k_scan_bsum requires nb<=256

    // --- CSR build (shared by both conv layers) ---
    k_zero<<<(N + B - 1) / B, B, 0, stream>>>(deg_cnt, N);
    k_count<<<(E + B - 1) / B, B, 0, stream>>>(dst, deg_cnt, E);
    k_scan_block<<<nb, 256, 0, stream>>>(deg_cnt, rowptr, bsum, N);
    k_scan_bsum<<<1, 256, 0, stream>>>(bsum, nb);
    k_finalize<<<(N + B - 1) / B, B, 0, stream>>>(rowptr, bsum, cursor, deg_cnt, dinv, N, E);
    k_scatter<<<(E + B - 1) / B, B, 0, stream>>>(src, dst, dinv, cursor, src_sorted, norm_sorted, E);

    // --- layer 1: h1 = x @ W1 ; a1 = agg(h1) + b1 ---
    float* h1 = bufA;
    float* a1 = bufB;
    k_gemm<FIN, FHID, false, false><<<(N + 31) / 32, B, 0, stream>>>(x, W1, nullptr, h1, N);
    k_agg_csr<FHID><<<((size_t)N * (FHID / 4) + B - 1) / B, B, 0, stream>>>(
        h1, rowptr, src_sorted, norm_sorted, dinv, b1, a1, N);

    // --- layer 2: h2 = relu(a1) @ W2 ; a2 = agg(h2) + b2 ---   (h2 aliases bufA, a2 aliases... bufA free after)
    float* h2 = bufA;  // h1 dead after agg-1
    k_gemm<FHID, FEMB, true, false><<<(N + 31) / 32, B, 0, stream>>>(a1, W2, nullptr, h2, N);
    float* a2 = bufB;  // a1 dead after gemm-2
    k_agg_csr<FEMB><<<((size_t)N * (FEMB / 4) + B - 1) / B, B, 0, stream>>>(
        h2, rowptr, src_sorted, norm_sorted, dinv, b2, a2, N);

    // --- classifier: out = relu(a2) @ Wc + bc ---
    k_gemm<FEMB, NCLS, true, true><<<(N + 31) / 32, B, 0, stream>>>(a2, Wc, bc, out, N);
}